// Round 1
// baseline (1448.695 us; speedup 1.0000x reference)
//
#include <hip/hip_runtime.h>
#include <hip/hip_bf16.h>
#include <cstdint>
#include <cstddef>

#define BB 32
#define LL 2048
#define DD 1024
#define HH 16
#define HDIM 64
#define NL 4
#define NCHUNK 8
#define CHUNK 256
#define NEGINF -1e30f

typedef __attribute__((ext_vector_type(8))) short bf16x8;
typedef __attribute__((ext_vector_type(4))) float f32x4;

__device__ __forceinline__ unsigned short f2b(float x) {
    union { float f; unsigned int u; } v; v.f = x;
    unsigned int r = (v.u + 0x7FFFu + ((v.u >> 16) & 1u)) >> 16;
    return (unsigned short)r;
}

// ---------------- layer-0 query projection: qh[b] = query_token @ Wq0 + bq0
__global__ __launch_bounds__(1024) void k_qh0(const float* __restrict__ qt,
        const float* __restrict__ Wq, const float* __restrict__ bq,
        float* __restrict__ qh) {
    int b = blockIdx.x, c = threadIdx.x;
    float acc = bq[c];
#pragma unroll 4
    for (int e = 0; e < DD; ++e) acc += qt[e] * Wq[(size_t)e * DD + c];
    qh[b * DD + c] = acc;
}

// ---------------- wk[b,h,e] = Wk[e, h*64:+64] . qh[b, h*64:+64]  (bf16 out) + sb
__global__ __launch_bounds__(256) void k_wk(const float* __restrict__ qh,
        const float* __restrict__ Wk, const float* __restrict__ bk,
        unsigned short* __restrict__ wk16, float* __restrict__ sb) {
    int h = blockIdx.x >> 3, et = blockIdx.x & 7;
    int tid = threadIdx.x;
    __shared__ float qs[BB][HDIM + 1];
    for (int i = tid; i < BB * HDIM; i += 256) {
        int bb = i >> 6, d = i & 63;
        qs[bb][d] = qh[bb * DD + h * HDIM + d];
    }
    __syncthreads();
    int b = tid & 31, eo = tid >> 5;
    for (int k = 0; k < 16; ++k) {
        int e = et * 128 + eo * 16 + k;
        const float* wrow = Wk + (size_t)e * DD + h * HDIM;
        float acc = 0.f;
#pragma unroll
        for (int d = 0; d < HDIM; ++d) acc += qs[b][d] * wrow[d];
        wk16[((size_t)(b * HH + h)) * DD + e] = f2b(acc);
    }
    if (et == 0 && tid < BB) {
        float acc = 0.f;
#pragma unroll
        for (int d = 0; d < HDIM; ++d) acc += qs[tid][d] * bk[h * HDIM + d];
        sb[tid * HH + h] = acc;
    }
}

// ---------------- main streaming attention pass (partial per (b, chunk))
__global__ __launch_bounds__(1024) void k_attn(const float* __restrict__ toks,
        const int* __restrict__ lens, const unsigned short* __restrict__ wk16,
        const float* __restrict__ sb, float* __restrict__ ctx_p,
        float* __restrict__ m_p, float* __restrict__ s_p) {
    int b = blockIdx.x >> 3, chunk = blockIdx.x & 7;
    int tid = threadIdx.x, lane = tid & 63, w = tid >> 6;
    int len = lens[b];
    int base = chunk * CHUNK;
    int pidx = (b * NCHUNK + chunk) * HH;
    if (base >= len) {
        if (tid < HH) { m_p[pidx + tid] = NEGINF; s_p[pidx + tid] = 0.f; }
        return;
    }
    int nv = min(CHUNK, len - base);

    __shared__ unsigned short Tcm[DD][34];     // [e][t] bf16, pad 34
    __shared__ float Sred[16][HH][34];         // per-wave partial scores
    __shared__ unsigned short Pt[HH][34];      // P^T bf16
    __shared__ float sm_m[HH], sm_s[HH], sm_c[HH];

    if (tid < HH) { sm_m[tid] = NEGINF; sm_s[tid] = 0.f; }

    int hq = lane & 15, qg = lane >> 4;
    // score A-fragments (wk), wave e-range [w*64, w*64+64)
    const unsigned short* wkb = wk16 + ((size_t)(b * HH + hq)) * DD + w * 64 + 8 * qg;
    bf16x8 afr0 = *(const bf16x8*)(wkb);
    bf16x8 afr1 = *(const bf16x8*)(wkb + 32);
    f32x4 zer = {0.f, 0.f, 0.f, 0.f};
    f32x4 ctxacc[4] = {zer, zer, zer, zer};
    float sbh = (tid < 512) ? sb[b * HH + (tid >> 5)] : 0.f;
    __syncthreads();

    for (int g = 0; g < 8; ++g) {
        int t0 = g * 32;
        if (t0 >= nv) break;
        // stage 32 tokens x 1024 dims, bf16, column-major [e][t]
        {
            const float* src = toks + ((size_t)b * LL + base + t0) * DD + tid;
#pragma unroll 8
            for (int t = 0; t < 32; ++t) Tcm[tid][t] = f2b(src[(size_t)t * DD]);
        }
        __syncthreads();
        // scores: S^T = wk @ T^T  (M=h, N=t, K=e)
        f32x4 s0 = zer, s1 = zer;
        {
            bf16x8 bfr;
            int eb = w * 64 + 8 * qg;
#pragma unroll
            for (int i = 0; i < 8; ++i) bfr[i] = (short)Tcm[eb + i][hq];
            s0 = __builtin_amdgcn_mfma_f32_16x16x32_bf16(afr0, bfr, s0, 0, 0, 0);
#pragma unroll
            for (int i = 0; i < 8; ++i) bfr[i] = (short)Tcm[eb + 32 + i][hq];
            s0 = __builtin_amdgcn_mfma_f32_16x16x32_bf16(afr1, bfr, s0, 0, 0, 0);
#pragma unroll
            for (int i = 0; i < 8; ++i) bfr[i] = (short)Tcm[eb + i][16 + hq];
            s1 = __builtin_amdgcn_mfma_f32_16x16x32_bf16(afr0, bfr, s1, 0, 0, 0);
#pragma unroll
            for (int i = 0; i < 8; ++i) bfr[i] = (short)Tcm[eb + 32 + i][16 + hq];
            s1 = __builtin_amdgcn_mfma_f32_16x16x32_bf16(afr1, bfr, s1, 0, 0, 0);
        }
#pragma unroll
        for (int r = 0; r < 4; ++r) {
            Sred[w][qg * 4 + r][hq] = s0[r];
            Sred[w][qg * 4 + r][16 + hq] = s1[r];
        }
        __syncthreads();
        // reduce across waves + online softmax (one thread per (h,t))
        if (tid < 512) {
            int h = tid >> 5, t = tid & 31;
            float s = 0.f;
#pragma unroll
            for (int ww = 0; ww < 16; ++ww) s += Sred[ww][h][t];
            s = (s + sbh) * 0.125f;
            bool valid = (t0 + t) < nv;
            if (!valid) s = NEGINF;
            float tm = s;
#pragma unroll
            for (int off = 16; off; off >>= 1) tm = fmaxf(tm, __shfl_xor(tm, off, 32));
            float oldm = sm_m[h];
            float newm = fmaxf(oldm, tm);
            float pv = valid ? __expf(s - newm) : 0.f;
            float ps = pv;
#pragma unroll
            for (int off = 16; off; off >>= 1) ps += __shfl_xor(ps, off, 32);
            if (t == 0) {
                float corr = __expf(oldm - newm);
                sm_c[h] = corr;
                sm_m[h] = newm;
                sm_s[h] = sm_s[h] * corr + ps;
            }
            Pt[h][t] = f2b(pv);
        }
        __syncthreads();
        // ctx: ctx(16 x e-slice) += P^T @ T   (M=h, N=e, K=t)
        {
            float cr[4];
#pragma unroll
            for (int r = 0; r < 4; ++r) cr[r] = sm_c[qg * 4 + r];
            bf16x8 pafr;
#pragma unroll
            for (int i = 0; i < 8; ++i) pafr[i] = (short)Pt[hq][8 * qg + i];
#pragma unroll
            for (int et = 0; et < 4; ++et) {
#pragma unroll
                for (int r = 0; r < 4; ++r) ctxacc[et][r] *= cr[r];
                bf16x8 bfr;
                int e = w * 64 + et * 16 + hq;
#pragma unroll
                for (int i = 0; i < 8; ++i) bfr[i] = (short)Tcm[e][8 * qg + i];
                ctxacc[et] = __builtin_amdgcn_mfma_f32_16x16x32_bf16(pafr, bfr, ctxacc[et], 0, 0, 0);
            }
        }
        __syncthreads();
    }
    if (tid < HH) { m_p[pidx + tid] = sm_m[tid]; s_p[pidx + tid] = sm_s[tid]; }
#pragma unroll
    for (int et = 0; et < 4; ++et)
#pragma unroll
        for (int r = 0; r < 4; ++r) {
            int h = qg * 4 + r, e = w * 64 + et * 16 + hq;
            ctx_p[((size_t)pidx + h) * DD + e] = ctxacc[et][r];
        }
}

// ---------------- combine chunk partials -> normalized ctx
__global__ __launch_bounds__(256) void k_comb(const float* __restrict__ m_p,
        const float* __restrict__ s_p, const float* __restrict__ ctx_p,
        float* __restrict__ ctxn) {
    int b = blockIdx.x >> 2, es = blockIdx.x & 3;
    int tid = threadIdx.x;
    __shared__ float wgt[NCHUNK][HH];
    __shared__ float mg[HH], Sg[HH];
    if (tid < HH) {
        float m = NEGINF;
        for (int c = 0; c < NCHUNK; ++c) m = fmaxf(m, m_p[(b * NCHUNK + c) * HH + tid]);
        float S = 0.f;
        for (int c = 0; c < NCHUNK; ++c)
            S += s_p[(b * NCHUNK + c) * HH + tid] * __expf(m_p[(b * NCHUNK + c) * HH + tid] - m);
        mg[tid] = m; Sg[tid] = S;
    }
    __syncthreads();
    if (tid < NCHUNK * HH) {
        int c = tid >> 4, h = tid & 15;
        wgt[c][h] = __expf(m_p[(b * NCHUNK + c) * HH + h] - mg[h]) / Sg[h];
    }
    __syncthreads();
    int e = es * 256 + tid;
    for (int h = 0; h < HH; ++h) {
        float acc = 0.f;
#pragma unroll
        for (int c = 0; c < NCHUNK; ++c)
            acc += wgt[c][h] * ctx_p[(((size_t)(b * NCHUNK + c)) * HH + h) * DD + e];
        ctxn[((size_t)(b * HH + h)) * DD + e] = acc;
    }
}

// ---------------- V projection: oattn[b, hd] = ctxn[b, h(hd), :] @ Wv[:, hd] + bv
__global__ __launch_bounds__(1024) void k_projv(const float* __restrict__ ctxn,
        const float* __restrict__ Wv, const float* __restrict__ bv,
        float* __restrict__ oattn) {
    int b = blockIdx.x, tid = threadIdx.x;
    int h = tid >> 6;
    const float* cr = ctxn + ((size_t)(b * HH + h)) * DD;
    float acc = bv[tid];
#pragma unroll 4
    for (int e = 0; e < DD; ++e) acc += cr[e] * Wv[(size_t)e * DD + tid];
    oattn[b * DD + tid] = acc;
}

// ---------------- O projection + LayerNorm + (next-layer) Q projection
__global__ __launch_bounds__(1024) void k_out(const float* __restrict__ oattn,
        const float* __restrict__ Wo, const float* __restrict__ bo,
        const float* __restrict__ gamma, const float* __restrict__ beta,
        const float* __restrict__ Wq2, const float* __restrict__ bq2,
        float* __restrict__ qh, float* __restrict__ outp, int last) {
    int b = blockIdx.x, tid = threadIdx.x;
    const float* ar = oattn + b * DD;
    float acc = bo[tid];
#pragma unroll 4
    for (int e = 0; e < DD; ++e) acc += ar[e] * Wo[(size_t)e * DD + tid];
    __shared__ float red1[16], red2[16];
    __shared__ float qs[DD];
    float v1 = acc, v2 = acc * acc;
#pragma unroll
    for (int off = 32; off; off >>= 1) { v1 += __shfl_xor(v1, off); v2 += __shfl_xor(v2, off); }
    int wv = tid >> 6;
    if ((tid & 63) == 0) { red1[wv] = v1; red2[wv] = v2; }
    __syncthreads();
    if (tid == 0) {
        float s1 = 0.f, s2 = 0.f;
        for (int i = 0; i < 16; ++i) { s1 += red1[i]; s2 += red2[i]; }
        red1[0] = s1 / DD; red2[0] = s2 / DD;
    }
    __syncthreads();
    float mu = red1[0], var = red2[0] - mu * mu;
    float g = (acc - mu) * rsqrtf(var + 1e-5f) * gamma[tid] + beta[tid];
    if (last) { outp[b * DD + tid] = g; return; }
    qs[tid] = g;
    __syncthreads();
    float qa = bq2[tid];
#pragma unroll 4
    for (int e = 0; e < DD; ++e) qa += qs[e] * Wq2[(size_t)e * DD + tid];
    qh[b * DD + tid] = qa;
}

extern "C" void kernel_launch(void* const* d_in, const int* in_sizes, int n_in,
                              void* d_out, int out_size, void* d_ws, size_t ws_size,
                              hipStream_t stream) {
    const float* toks  = (const float*)d_in[0];
    const int*   lens  = (const int*)d_in[1];
    const float* qt    = (const float*)d_in[2];
    const float* Wq    = (const float*)d_in[3];
    const float* bq    = (const float*)d_in[4];
    const float* Wk    = (const float*)d_in[5];
    const float* bk    = (const float*)d_in[6];
    const float* Wv    = (const float*)d_in[7];
    const float* bv    = (const float*)d_in[8];
    const float* Wo    = (const float*)d_in[9];
    const float* bo    = (const float*)d_in[10];
    const float* gamma = (const float*)d_in[11];
    const float* beta  = (const float*)d_in[12];
    float* out = (float*)d_out;
    float* ws  = (float*)d_ws;

    float* ctx_p = ws;                         // 32*8*16*1024 = 4194304 floats
    float* m_p   = ws + 4194304;               // 4096
    float* s_p   = ws + 4198400;               // 4096
    float* ctxn  = ws + 4202496;               // 524288
    float* oattn = ws + 4726784;               // 32768
    float* qh    = ws + 4759552;               // 32768
    float* sbuf  = ws + 4792320;               // 512
    unsigned short* wk16 = (unsigned short*)(ws + 4792832);  // 524288 u16

    k_qh0<<<32, 1024, 0, stream>>>(qt, Wq, bq, qh);
    for (int i = 0; i < NL; ++i) {
        k_wk<<<128, 256, 0, stream>>>(qh, Wk + (size_t)i * DD * DD, bk + i * DD, wk16, sbuf);
        k_attn<<<256, 1024, 0, stream>>>(toks, lens, wk16, sbuf, ctx_p, m_p, s_p);
        k_comb<<<128, 256, 0, stream>>>(m_p, s_p, ctx_p, ctxn);
        k_projv<<<32, 1024, 0, stream>>>(ctxn, Wv + (size_t)i * DD * DD, bv + i * DD, oattn);
        int last = (i == NL - 1);
        k_out<<<32, 1024, 0, stream>>>(oattn, Wo + (size_t)i * DD * DD, bo + i * DD,
                gamma + i * DD, beta + i * DD,
                last ? Wq : (Wq + (size_t)(i + 1) * DD * DD),
                last ? bq : (bq + (i + 1) * DD),
                qh, out, last);
    }
}

// Round 2
// 446.334 us; speedup vs baseline: 3.2458x; 3.2458x over previous
//
#include <hip/hip_runtime.h>
#include <hip/hip_bf16.h>
#include <cstdint>
#include <cstddef>

#define BB 32
#define LL 2048
#define DD 1024
#define HH 16
#define HDIM 64
#define NL 4
#define NCHUNK 8
#define CHUNK 256
#define NEGINF -1e30f
#define KS 16          // K-splits for GEMVs
#define KLEN 64        // 1024 / KS

typedef __attribute__((ext_vector_type(8))) short bf16x8;
typedef __attribute__((ext_vector_type(4))) float f32x4;

__device__ __forceinline__ unsigned short f2b(float x) {
    union { float f; unsigned int u; } v; v.f = x;
    unsigned int r = (v.u + 0x7FFFu + ((v.u >> 16) & 1u)) >> 16;
    return (unsigned short)r;
}

// ---------------- fp32 -> bf16 token cache
__global__ __launch_bounds__(256) void k_conv(const float* __restrict__ t,
        unsigned short* __restrict__ c, size_t n8) {
    size_t stride = (size_t)gridDim.x * blockDim.x;
    for (size_t i = (size_t)blockIdx.x * blockDim.x + threadIdx.x; i < n8; i += stride) {
        const float4 a0 = *(const float4*)(t + i * 8);
        const float4 a1 = *(const float4*)(t + i * 8 + 4);
        ushort4 u0, u1;
        u0.x = f2b(a0.x); u0.y = f2b(a0.y); u0.z = f2b(a0.z); u0.w = f2b(a0.w);
        u1.x = f2b(a1.x); u1.y = f2b(a1.y); u1.z = f2b(a1.z); u1.w = f2b(a1.w);
        *(ushort4*)(c + i * 8) = u0;
        *(ushort4*)(c + i * 8 + 4) = u1;
    }
}

// ---------------- g0[b][c] = qt[c]
__global__ __launch_bounds__(256) void k_bcast(const float* __restrict__ qt,
        float* __restrict__ g0) {
    int i = blockIdx.x * 256 + threadIdx.x;
    g0[i] = qt[i & (DD - 1)];
}

// ---------------- split-K GEMV partials: part[ks][b][c] = X[b, ks*64:+64] @ W[.., c]
// SRC 0: X = Xg (plain [32][1024])
// SRC 1: X = (Xg - mu)*rstd*gamma + beta   (LayerNorm applied on the fly)
// SRC 2: X = bias + sum_ks' parts_in       (combine previous partials)
// SRC 3: X = sum_c8 wgt[b][c8]*ctx_p[...]  (softmax chunk combine; head = col-tile)
template<int SRC>
__global__ __launch_bounds__(256) void k_gemv(
        const float* __restrict__ Xg,
        const float* __restrict__ stats, const float* __restrict__ gamma,
        const float* __restrict__ beta,
        const float* __restrict__ parts_in, const float* __restrict__ bias_in,
        const float* __restrict__ ctx_p, const float* __restrict__ m_p,
        const float* __restrict__ s_p,
        const float* __restrict__ W, float* __restrict__ outp) {
    int bid = blockIdx.x, tid = threadIdx.x;
    int ct = bid & 15, ks = bid >> 4;
    int e0 = ks * KLEN;
    __shared__ float Xs[BB][KLEN];
    __shared__ float wgtS[BB][NCHUNK];
    __shared__ float mgS[BB], SgS[BB];
    if (SRC == 3) {
        if (tid < BB) {
            int b = tid; float m = NEGINF;
            for (int c8 = 0; c8 < NCHUNK; ++c8)
                m = fmaxf(m, m_p[(b * NCHUNK + c8) * HH + ct]);
            float S = 0.f;
            for (int c8 = 0; c8 < NCHUNK; ++c8)
                S += s_p[(b * NCHUNK + c8) * HH + ct] *
                     __expf(m_p[(b * NCHUNK + c8) * HH + ct] - m);
            mgS[b] = m; SgS[b] = S;
        }
        __syncthreads();
        {
            int b = tid >> 3, c8 = tid & 7;
            wgtS[b][c8] = __expf(m_p[(b * NCHUNK + c8) * HH + ct] - mgS[b]) / SgS[b];
        }
        __syncthreads();
    }
    // stage Xs[32][64]
#pragma unroll
    for (int j = 0; j < 8; ++j) {
        int i = tid + j * 256;
        int b = i >> 6, k = i & 63;
        float x;
        if (SRC == 0) {
            x = Xg[(size_t)b * DD + e0 + k];
        } else if (SRC == 1) {
            float mu = stats[b * 2], rstd = stats[b * 2 + 1];
            x = (Xg[(size_t)b * DD + e0 + k] - mu) * rstd * gamma[e0 + k] + beta[e0 + k];
        } else if (SRC == 2) {
            x = bias_in[e0 + k];
#pragma unroll
            for (int j2 = 0; j2 < KS; ++j2)
                x += parts_in[((size_t)(j2 * BB) + b) * DD + e0 + k];
        } else {
            x = 0.f;
#pragma unroll
            for (int c8 = 0; c8 < NCHUNK; ++c8)
                x += wgtS[b][c8] *
                     ctx_p[(((size_t)(b * NCHUNK + c8)) * HH + ct) * DD + e0 + k];
        }
        Xs[b][k] = x;
    }
    __syncthreads();
    int col = tid & 63, bg = tid >> 6;
    int c = ct * 64 + col;
    float acc[8] = {0.f, 0.f, 0.f, 0.f, 0.f, 0.f, 0.f, 0.f};
    for (int k = 0; k < KLEN; k += 4) {
        float w0 = W[(size_t)(e0 + k) * DD + c];
        float w1 = W[(size_t)(e0 + k + 1) * DD + c];
        float w2 = W[(size_t)(e0 + k + 2) * DD + c];
        float w3 = W[(size_t)(e0 + k + 3) * DD + c];
#pragma unroll
        for (int bb = 0; bb < 8; ++bb) {
            const float4 xv = *(const float4*)&Xs[bg * 8 + bb][k];
            acc[bb] += xv.x * w0 + xv.y * w1 + xv.z * w2 + xv.w * w3;
        }
    }
#pragma unroll
    for (int bb = 0; bb < 8; ++bb)
        outp[((size_t)(ks * BB) + bg * 8 + bb) * DD + c] = acc[bb];
}

// ---------------- combine partials + bias -> Y[32][1024]
__global__ __launch_bounds__(256) void k_comb_bias(const float* __restrict__ parts,
        const float* __restrict__ bias, float* __restrict__ Y) {
    int i = blockIdx.x * 256 + threadIdx.x;
    int b = i >> 10, c = i & (DD - 1);
    float v = bias[c];
#pragma unroll
    for (int ks = 0; ks < KS; ++ks)
        v += parts[((size_t)(ks * BB) + b) * DD + c];
    Y[i] = v;
}

// ---------------- combine partials + bias -> oraw + LN stats
__global__ __launch_bounds__(256) void k_stats(const float* __restrict__ parts,
        const float* __restrict__ bo, float* __restrict__ oraw,
        float* __restrict__ stats) {
    int b = blockIdx.x, tid = threadIdx.x;
    float s1 = 0.f, s2 = 0.f;
#pragma unroll
    for (int j = 0; j < 4; ++j) {
        int c = tid + j * 256;
        float v = bo[c];
#pragma unroll
        for (int ks = 0; ks < KS; ++ks)
            v += parts[((size_t)(ks * BB) + b) * DD + c];
        oraw[(size_t)b * DD + c] = v;
        s1 += v; s2 += v * v;
    }
#pragma unroll
    for (int off = 32; off; off >>= 1) {
        s1 += __shfl_xor(s1, off);
        s2 += __shfl_xor(s2, off);
    }
    __shared__ float r1[4], r2[4];
    int w = tid >> 6;
    if ((tid & 63) == 0) { r1[w] = s1; r2[w] = s2; }
    __syncthreads();
    if (tid == 0) {
        float a = r1[0] + r1[1] + r1[2] + r1[3];
        float q = r2[0] + r2[1] + r2[2] + r2[3];
        float mu = a / (float)DD, var = q / (float)DD - mu * mu;
        stats[b * 2] = mu;
        stats[b * 2 + 1] = rsqrtf(var + 1e-5f);
    }
}

// ---------------- final LN apply
__global__ __launch_bounds__(256) void k_final(const float* __restrict__ oraw,
        const float* __restrict__ stats, const float* __restrict__ gamma,
        const float* __restrict__ beta, float* __restrict__ outp) {
    int i = blockIdx.x * 256 + threadIdx.x;
    int b = i >> 10, c = i & (DD - 1);
    outp[i] = (oraw[i] - stats[b * 2]) * stats[b * 2 + 1] * gamma[c] + beta[c];
}

// ---------------- wk[b,h,e] = Wk[e, h*64:+64] . qh[b, h*64:+64]  (bf16 out) + sb
__global__ __launch_bounds__(256) void k_wk(const float* __restrict__ qh,
        const float* __restrict__ Wk, const float* __restrict__ bk,
        unsigned short* __restrict__ wk16, float* __restrict__ sb) {
    int h = blockIdx.x >> 3, et = blockIdx.x & 7;
    int tid = threadIdx.x;
    __shared__ float qs[BB][HDIM + 1];
    for (int i = tid; i < BB * HDIM; i += 256) {
        int bb = i >> 6, d = i & 63;
        qs[bb][d] = qh[bb * DD + h * HDIM + d];
    }
    __syncthreads();
    int b = tid & 31, eo = tid >> 5;
    for (int k = 0; k < 16; ++k) {
        int e = et * 128 + eo * 16 + k;
        const float* wrow = Wk + (size_t)e * DD + h * HDIM;
        float acc = 0.f;
#pragma unroll
        for (int d = 0; d < HDIM; ++d) acc += qs[b][d] * wrow[d];
        wk16[((size_t)(b * HH + h)) * DD + e] = f2b(acc);
    }
    if (et == 0 && tid < BB) {
        float acc = 0.f;
#pragma unroll
        for (int d = 0; d < HDIM; ++d) acc += qs[tid][d] * bk[h * HDIM + d];
        sb[tid * HH + h] = acc;
    }
}

// ---------------- main streaming attention pass (partial per (b, chunk))
template<int CACHE>
__global__ __launch_bounds__(1024) void k_attn(const float* __restrict__ toks,
        const unsigned short* __restrict__ tcache,
        const int* __restrict__ lens, const unsigned short* __restrict__ wk16,
        const float* __restrict__ sb, float* __restrict__ ctx_p,
        float* __restrict__ m_p, float* __restrict__ s_p) {
    int b = blockIdx.x >> 3, chunk = blockIdx.x & 7;
    int tid = threadIdx.x, lane = tid & 63, w = tid >> 6;
    int len = lens[b];
    int base = chunk * CHUNK;
    int pidx = (b * NCHUNK + chunk) * HH;
    if (base >= len) {
        if (tid < HH) { m_p[pidx + tid] = NEGINF; s_p[pidx + tid] = 0.f; }
        return;
    }
    int nv = min(CHUNK, len - base);

    __shared__ unsigned short Tcm[DD][34];
    __shared__ float Sred[16][HH][34];
    __shared__ unsigned short Pt[HH][34];
    __shared__ float sm_m[HH], sm_s[HH], sm_c[HH];

    if (tid < HH) { sm_m[tid] = NEGINF; sm_s[tid] = 0.f; }

    int hq = lane & 15, qg = lane >> 4;
    const unsigned short* wkb = wk16 + ((size_t)(b * HH + hq)) * DD + w * 64 + 8 * qg;
    bf16x8 afr0 = *(const bf16x8*)(wkb);
    bf16x8 afr1 = *(const bf16x8*)(wkb + 32);
    f32x4 zer = {0.f, 0.f, 0.f, 0.f};
    f32x4 ctxacc[4] = {zer, zer, zer, zer};
    float sbh = (tid < 512) ? sb[b * HH + (tid >> 5)] : 0.f;
    __syncthreads();

    for (int g = 0; g < 8; ++g) {
        int t0 = g * 32;
        if (t0 >= nv) break;
        if (CACHE) {
            const unsigned short* src = tcache + ((size_t)b * LL + base + t0) * DD + tid;
#pragma unroll 8
            for (int t = 0; t < 32; ++t) Tcm[tid][t] = src[(size_t)t * DD];
        } else {
            const float* src = toks + ((size_t)b * LL + base + t0) * DD + tid;
#pragma unroll 8
            for (int t = 0; t < 32; ++t) Tcm[tid][t] = f2b(src[(size_t)t * DD]);
        }
        __syncthreads();
        f32x4 s0 = zer, s1 = zer;
        {
            bf16x8 bfr;
            int eb = w * 64 + 8 * qg;
#pragma unroll
            for (int i = 0; i < 8; ++i) bfr[i] = (short)Tcm[eb + i][hq];
            s0 = __builtin_amdgcn_mfma_f32_16x16x32_bf16(afr0, bfr, s0, 0, 0, 0);
#pragma unroll
            for (int i = 0; i < 8; ++i) bfr[i] = (short)Tcm[eb + 32 + i][hq];
            s0 = __builtin_amdgcn_mfma_f32_16x16x32_bf16(afr1, bfr, s0, 0, 0, 0);
#pragma unroll
            for (int i = 0; i < 8; ++i) bfr[i] = (short)Tcm[eb + i][16 + hq];
            s1 = __builtin_amdgcn_mfma_f32_16x16x32_bf16(afr0, bfr, s1, 0, 0, 0);
#pragma unroll
            for (int i = 0; i < 8; ++i) bfr[i] = (short)Tcm[eb + 32 + i][16 + hq];
            s1 = __builtin_amdgcn_mfma_f32_16x16x32_bf16(afr1, bfr, s1, 0, 0, 0);
        }
#pragma unroll
        for (int r = 0; r < 4; ++r) {
            Sred[w][qg * 4 + r][hq] = s0[r];
            Sred[w][qg * 4 + r][16 + hq] = s1[r];
        }
        __syncthreads();
        if (tid < 512) {
            int h = tid >> 5, t = tid & 31;
            float s = 0.f;
#pragma unroll
            for (int ww = 0; ww < 16; ++ww) s += Sred[ww][h][t];
            s = (s + sbh) * 0.125f;
            bool valid = (t0 + t) < nv;
            if (!valid) s = NEGINF;
            float tm = s;
#pragma unroll
            for (int off = 16; off; off >>= 1) tm = fmaxf(tm, __shfl_xor(tm, off, 32));
            float oldm = sm_m[h];
            float newm = fmaxf(oldm, tm);
            float pv = valid ? __expf(s - newm) : 0.f;
            float ps = pv;
#pragma unroll
            for (int off = 16; off; off >>= 1) ps += __shfl_xor(ps, off, 32);
            if (t == 0) {
                float corr = __expf(oldm - newm);
                sm_c[h] = corr;
                sm_m[h] = newm;
                sm_s[h] = sm_s[h] * corr + ps;
            }
            Pt[h][t] = f2b(pv);
        }
        __syncthreads();
        {
            float cr[4];
#pragma unroll
            for (int r = 0; r < 4; ++r) cr[r] = sm_c[qg * 4 + r];
            bf16x8 pafr;
#pragma unroll
            for (int i = 0; i < 8; ++i) pafr[i] = (short)Pt[hq][8 * qg + i];
#pragma unroll
            for (int et = 0; et < 4; ++et) {
#pragma unroll
                for (int r = 0; r < 4; ++r) ctxacc[et][r] *= cr[r];
                bf16x8 bfr;
                int e = w * 64 + et * 16 + hq;
#pragma unroll
                for (int i = 0; i < 8; ++i) bfr[i] = (short)Tcm[e][8 * qg + i];
                ctxacc[et] = __builtin_amdgcn_mfma_f32_16x16x32_bf16(pafr, bfr, ctxacc[et], 0, 0, 0);
            }
        }
        __syncthreads();
    }
    if (tid < HH) { m_p[pidx + tid] = sm_m[tid]; s_p[pidx + tid] = sm_s[tid]; }
#pragma unroll
    for (int et = 0; et < 4; ++et)
#pragma unroll
        for (int r = 0; r < 4; ++r) {
            int h = qg * 4 + r, e = w * 64 + et * 16 + hq;
            ctx_p[((size_t)pidx + h) * DD + e] = ctxacc[et][r];
        }
}

extern "C" void kernel_launch(void* const* d_in, const int* in_sizes, int n_in,
                              void* d_out, int out_size, void* d_ws, size_t ws_size,
                              hipStream_t stream) {
    const float* toks  = (const float*)d_in[0];
    const int*   lens  = (const int*)d_in[1];
    const float* qt    = (const float*)d_in[2];
    const float* Wq    = (const float*)d_in[3];
    const float* bq    = (const float*)d_in[4];
    const float* Wk    = (const float*)d_in[5];
    const float* bk    = (const float*)d_in[6];
    const float* Wv    = (const float*)d_in[7];
    const float* bv    = (const float*)d_in[8];
    const float* Wo    = (const float*)d_in[9];
    const float* bo    = (const float*)d_in[10];
    const float* gamma = (const float*)d_in[11];
    const float* beta  = (const float*)d_in[12];
    float* out = (float*)d_out;
    float* ws  = (float*)d_ws;

    // ws layout (floats)
    float* ctx_p = ws;                       // 4194304
    float* m_p   = ws + 4194304;             // 4096
    float* s_p   = ws + 4198400;             // 4096
    float* pvp   = ws + 4202496;             // 524288  (aliased as qp)
    float* op    = ws + 4726784;             // 524288
    float* oraw  = ws + 5251072;             // 32768   (aliased as g0)
    float* stats = ws + 5283840;             // 64
    float* qh    = ws + 5283904;             // 32768
    float* sbuf  = ws + 5316672;             // 512
    unsigned short* wk16 = (unsigned short*)(ws + 5317184);  // 524288 u16
    const size_t base_floats = 5579328;
    unsigned short* tcache = (unsigned short*)(ws + base_floats);
    const size_t need_cache = base_floats * 4 + (size_t)BB * LL * DD * 2;
    const bool use_cache = (ws_size >= need_cache);

    float* qp = pvp;
    float* g0 = oraw;

    if (use_cache)
        k_conv<<<4096, 256, 0, stream>>>(toks, tcache, (size_t)BB * LL * DD / 8);

    // prologue: qh = qt @ Wq0 + bq0 (broadcast over b)
    k_bcast<<<128, 256, 0, stream>>>(qt, g0);
    k_gemv<0><<<256, 256, 0, stream>>>(g0, nullptr, nullptr, nullptr, nullptr,
            nullptr, nullptr, nullptr, nullptr, Wq, qp);
    k_comb_bias<<<128, 256, 0, stream>>>(qp, bq, qh);

    for (int i = 0; i < NL; ++i) {
        const float* Wk_i = Wk + (size_t)i * DD * DD;
        const float* Wv_i = Wv + (size_t)i * DD * DD;
        const float* Wo_i = Wo + (size_t)i * DD * DD;
        k_wk<<<128, 256, 0, stream>>>(qh, Wk_i, bk + i * DD, wk16, sbuf);
        if (use_cache)
            k_attn<1><<<256, 1024, 0, stream>>>(toks, tcache, lens, wk16, sbuf,
                    ctx_p, m_p, s_p);
        else
            k_attn<0><<<256, 1024, 0, stream>>>(toks, tcache, lens, wk16, sbuf,
                    ctx_p, m_p, s_p);
        // pv: ctx (chunk-combined on the fly) @ Wv -> pvp
        k_gemv<3><<<256, 256, 0, stream>>>(nullptr, nullptr, nullptr, nullptr,
                nullptr, nullptr, ctx_p, m_p, s_p, Wv_i, pvp);
        // o: (pv combined + bv) @ Wo -> op
        k_gemv<2><<<256, 256, 0, stream>>>(nullptr, nullptr, nullptr, nullptr,
                pvp, bv + i * DD, nullptr, nullptr, nullptr, Wo_i, op);
        // combine + bo -> oraw, LN stats
        k_stats<<<32, 256, 0, stream>>>(op, bo + i * DD, oraw, stats);
        if (i == NL - 1) {
            k_final<<<128, 256, 0, stream>>>(oraw, stats, gamma + i * DD,
                    beta + i * DD, out);
        } else {
            // q_{i+1}: LN(oraw) @ Wq_{i+1} -> qp, then + bq -> qh
            k_gemv<1><<<256, 256, 0, stream>>>(oraw, stats, gamma + i * DD,
                    beta + i * DD, nullptr, nullptr, nullptr, nullptr, nullptr,
                    Wq + (size_t)(i + 1) * DD * DD, qp);
            k_comb_bias<<<128, 256, 0, stream>>>(qp, bq + (i + 1) * DD, qh);
        }
    }
}